// Round 2
// baseline (951.073 us; speedup 1.0000x reference)
//
#include <hip/hip_runtime.h>
#include <hip/hip_bf16.h>
#include <stdint.h>

// ---------------- GEMM: out[n,COUT] = X[n,K] @ W[K,COUT] (+bias), fp32 ----------------
template<int K, int COUT, bool ADD_BIAS>
__global__ __launch_bounds__(256) void gemm_kernel(const float* __restrict__ X,
                                                   const float* __restrict__ W,
                                                   const float* __restrict__ bias,
                                                   float* __restrict__ out, int n)
{
    constexpr int KC   = 64;                      // K-chunk staged per pass
    constexpr int CPT  = (COUT >= 128) ? 8 : 4;   // cols per thread
    constexpr int TX   = COUT / CPT;              // 16
    constexpr int TY   = 256 / TX;                // 16
    constexpr int ROWS = TY * 4;                  // 64 rows per block

    __shared__ float Wl[KC * COUT];               // <= 32 KB
    __shared__ float Xl[ROWS * KC];               // 16 KB

    const int tid  = threadIdx.x;
    const int row0 = blockIdx.x * ROWS;
    const int tx = tid % TX, ty = tid / TX;
    const int c0 = tx * CPT;

    float acc[4][CPT];
    #pragma unroll
    for (int i = 0; i < 4; ++i)
        #pragma unroll
        for (int j = 0; j < CPT; ++j) acc[i][j] = 0.f;

    for (int k0 = 0; k0 < K; k0 += KC) {
        // stage W chunk [KC x COUT]
        for (int i = tid; i < KC * COUT / 4; i += 256) {
            int e0 = i * 4;
            int r = e0 / COUT, c = e0 - r * COUT;
            reinterpret_cast<float4*>(Wl)[i] =
                *reinterpret_cast<const float4*>(W + (size_t)(k0 + r) * COUT + c);
        }
        // stage X chunk [ROWS x KC]
        for (int i = tid; i < ROWS * KC / 4; i += 256) {
            int r = i / (KC / 4), c4 = i - r * (KC / 4);
            int gr = row0 + r;
            float4 v = make_float4(0.f, 0.f, 0.f, 0.f);
            if (gr < n) v = *reinterpret_cast<const float4*>(X + (size_t)gr * K + k0 + c4 * 4);
            reinterpret_cast<float4*>(Xl)[i] = v;
        }
        __syncthreads();

        #pragma unroll 16
        for (int kk = 0; kk < KC; ++kk) {
            float b[CPT];
            #pragma unroll
            for (int j = 0; j < CPT; ++j) b[j] = Wl[kk * COUT + c0 + j];
            float a[4];
            #pragma unroll
            for (int i = 0; i < 4; ++i) a[i] = Xl[(ty * 4 + i) * KC + kk];
            #pragma unroll
            for (int i = 0; i < 4; ++i)
                #pragma unroll
                for (int j = 0; j < CPT; ++j)
                    acc[i][j] = fmaf(a[i], b[j], acc[i][j]);
        }
        __syncthreads();
    }

    #pragma unroll
    for (int i = 0; i < 4; ++i) {
        int gr = row0 + ty * 4 + i;
        if (gr < n) {
            #pragma unroll
            for (int j = 0; j < CPT; ++j) {
                float v = acc[i][j];
                if constexpr (ADD_BIAS) v += bias[c0 + j];
                out[(size_t)gr * COUT + c0 + j] = v;
            }
        }
    }
}

// ---------------- attention scalars: s/d[n,H] = sum_c h[n,h,c]*a[h,c] ----------------
template<int C, int H>
__global__ __launch_bounds__(256) void sd_kernel(const float* __restrict__ hfeat,
                                                 const float* __restrict__ asrc,
                                                 const float* __restrict__ adst,
                                                 float* __restrict__ s,
                                                 float* __restrict__ d, int n)
{
    constexpr int CH = C / H;
    int t = blockIdx.x * 256 + threadIdx.x;
    if (t >= n * H) return;
    int node = t / H, hh = t - (t / H) * H;
    const float* hp = hfeat + (size_t)node * C + hh * CH;
    float as = 0.f, ad = 0.f;
    #pragma unroll
    for (int c = 0; c < CH; ++c) {
        float hv = hp[c];
        as = fmaf(hv, asrc[hh * CH + c], as);
        ad = fmaf(hv, adst[hh * CH + c], ad);
    }
    s[t] = as; d[t] = ad;
}

// ---------------- CSR build ----------------
__global__ __launch_bounds__(256) void count_kernel(const int* __restrict__ dst,
                                                    int* __restrict__ cnt, int e)
{
    int t = blockIdx.x * 256 + threadIdx.x;
    if (t < e) atomicAdd(&cnt[dst[t]], 1);
}

__global__ __launch_bounds__(1024) void chunk_sum_kernel(const int* __restrict__ cnt,
                                                         int* __restrict__ bsum, int n)
{
    __shared__ int red[1024];
    int i = blockIdx.x * 1024 + threadIdx.x;
    red[threadIdx.x] = (i < n) ? cnt[i] : 0;
    __syncthreads();
    for (int o = 512; o > 0; o >>= 1) {
        if (threadIdx.x < o) red[threadIdx.x] += red[threadIdx.x + o];
        __syncthreads();
    }
    if (threadIdx.x == 0) bsum[blockIdx.x] = red[0];
}

__global__ __launch_bounds__(1024) void scan_blocks_kernel(const int* __restrict__ bsum,
                                                           int* __restrict__ boffs,
                                                           int* __restrict__ roff,
                                                           int nb, int n)
{
    __shared__ int tmp[1024];
    int tid = threadIdx.x;
    int v = (tid < nb) ? bsum[tid] : 0;
    tmp[tid] = v; __syncthreads();
    for (int o = 1; o < 1024; o <<= 1) {
        int x = (tid >= o) ? tmp[tid - o] : 0;
        __syncthreads();
        tmp[tid] += x;
        __syncthreads();
    }
    boffs[tid] = tmp[tid] - v;          // exclusive block offset
    if (tid == 0) roff[n] = tmp[1023];  // total == E
}

__global__ __launch_bounds__(1024) void scan_chunk_kernel(const int* __restrict__ cnt,
                                                          const int* __restrict__ boffs,
                                                          int* __restrict__ roff, int n)
{
    __shared__ int tmp[1024];
    int tid = threadIdx.x;
    int i = blockIdx.x * 1024 + tid;
    int v = (i < n) ? cnt[i] : 0;
    tmp[tid] = v; __syncthreads();
    for (int o = 1; o < 1024; o <<= 1) {
        int x = (tid >= o) ? tmp[tid - o] : 0;
        __syncthreads();
        tmp[tid] += x;
        __syncthreads();
    }
    if (i < n) roff[i] = boffs[blockIdx.x] + tmp[tid] - v;  // global exclusive prefix
}

__global__ __launch_bounds__(256) void scatter_kernel(const int* __restrict__ src,
                                                      const int* __restrict__ dst,
                                                      const int* __restrict__ roff,
                                                      int* __restrict__ cursor,
                                                      int* __restrict__ col, int e)
{
    int t = blockIdx.x * 256 + threadIdx.x;
    if (t < e) {
        int d0 = dst[t];
        int pos = roff[d0] + atomicAdd(&cursor[d0], 1);
        col[pos] = src[t];
    }
}

// ---------------- GAT aggregation: one wave per destination node ----------------
template<int C, int H, bool ELU>
__global__ __launch_bounds__(256) void agg_kernel(const float* __restrict__ hfeat,
                                                  const float* __restrict__ sarr,
                                                  const float* __restrict__ darr,
                                                  const int* __restrict__ roff,
                                                  const int* __restrict__ col,
                                                  const float* __restrict__ bias,
                                                  float* __restrict__ out, int n)
{
    constexpr int CPL = C / 64;   // cols per lane (2 or 1)
    constexpr int CH  = C / H;
    const int wv   = (blockIdx.x * 256 + threadIdx.x) >> 6;
    const int lane = threadIdx.x & 63;
    if (wv >= n) return;
    const int i = wv;

    float dh[H], es[H], mh[H];
    #pragma unroll
    for (int hh = 0; hh < H; ++hh) dh[hh] = darr[(size_t)i * H + hh];
    #pragma unroll
    for (int hh = 0; hh < H; ++hh) {
        float e = sarr[(size_t)i * H + hh] + dh[hh];
        e = fmaxf(e, 0.2f * e);               // leaky_relu(0.2) -- self loop
        es[hh] = e; mh[hh] = e;
    }
    const int start = roff[i], end = roff[i + 1];

    // pass 1: segment max per head
    for (int base = start; base < end; base += 64) {
        int idx = base + lane;
        if (idx < end) {
            int src = col[idx];
            #pragma unroll
            for (int hh = 0; hh < H; ++hh) {
                float e = sarr[(size_t)src * H + hh] + dh[hh];
                e = fmaxf(e, 0.2f * e);
                mh[hh] = fmaxf(mh[hh], e);
            }
        }
    }
    #pragma unroll
    for (int hh = 0; hh < H; ++hh)
        for (int o = 32; o >= 1; o >>= 1)
            mh[hh] = fmaxf(mh[hh], __shfl_xor(mh[hh], o, 64));

    // pass 2: sum of exp
    float zh[H];
    #pragma unroll
    for (int hh = 0; hh < H; ++hh) zh[hh] = 0.f;
    for (int base = start; base < end; base += 64) {
        int idx = base + lane;
        if (idx < end) {
            int src = col[idx];
            #pragma unroll
            for (int hh = 0; hh < H; ++hh) {
                float e = sarr[(size_t)src * H + hh] + dh[hh];
                e = fmaxf(e, 0.2f * e);
                zh[hh] += __expf(e - mh[hh]);
            }
        }
    }
    #pragma unroll
    for (int hh = 0; hh < H; ++hh) {
        for (int o = 32; o >= 1; o >>= 1) zh[hh] += __shfl_xor(zh[hh], o, 64);
        zh[hh] += __expf(es[hh] - mh[hh]);    // self-loop term (uniform across lanes)
    }

    // lane-local head parameters
    const int c0 = lane * CPL;
    const int hd = c0 / CH;
    const float m_l  = mh[hd];
    const float invz = 1.f / (zh[hd] + 1e-16f);
    const float d_l  = dh[hd];

    float acc[CPL];
    {
        float aself = __expf(es[hd] - m_l) * invz;
        if constexpr (CPL == 2) {
            float2 hv = reinterpret_cast<const float2*>(hfeat + (size_t)i * C)[lane];
            acc[0] = aself * hv.x; acc[1] = aself * hv.y;
        } else {
            acc[0] = aself * hfeat[(size_t)i * C + lane];
        }
    }

    // pass 3: weighted accumulate, edge-serial within wave
    for (int base = start; base < end; base += 64) {
        int idx = base + lane;
        int srcL = (idx < end) ? col[idx] : 0;
        int cnt2 = min(64, end - base);
        for (int t = 0; t < cnt2; ++t) {
            int st = __shfl(srcL, t, 64);
            float e = sarr[(size_t)st * H + hd] + d_l;
            e = fmaxf(e, 0.2f * e);
            float a = __expf(e - m_l) * invz;
            if constexpr (CPL == 2) {
                float2 hv = reinterpret_cast<const float2*>(hfeat + (size_t)st * C)[lane];
                acc[0] = fmaf(a, hv.x, acc[0]);
                acc[1] = fmaf(a, hv.y, acc[1]);
            } else {
                acc[0] = fmaf(a, hfeat[(size_t)st * C + lane], acc[0]);
            }
        }
    }

    #pragma unroll
    for (int j = 0; j < CPL; ++j) {
        int c = c0 + j;
        float v = acc[j] + bias[c];
        if constexpr (ELU) v = (v > 0.f) ? v : (__expf(v) - 1.f);
        out[(size_t)i * C + c] = v;
    }
}

// ---------------- edge logits: wave per edge, 64-dim dot ----------------
__global__ __launch_bounds__(256) void logits_kernel(const float* __restrict__ zp,
                                                     const float* __restrict__ zm,
                                                     const int* __restrict__ prov,
                                                     const int* __restrict__ memb,
                                                     float* __restrict__ outv, int e)
{
    int wv = (blockIdx.x * 256 + threadIdx.x) >> 6;
    int lane = threadIdx.x & 63;
    if (wv >= e) return;
    int p = prov[wv], m = memb[wv];
    float v = zp[(size_t)p * 64 + lane] * zm[(size_t)m * 64 + lane];
    for (int o = 32; o >= 1; o >>= 1) v += __shfl_xor(v, o, 64);
    if (lane == 0) outv[wv] = v;
}

// ---------------- launch ----------------
extern "C" void kernel_launch(void* const* d_in, const int* in_sizes, int n_in,
                              void* d_out, int out_size, void* d_ws, size_t ws_size,
                              hipStream_t stream)
{
    const int N_ = in_sizes[0] / 128;
    const int E_ = in_sizes[2] / 2;

    const float* x_member   = (const float*)d_in[0];
    const float* x_provider = (const float*)d_in[1];
    const int*   prov = (const int*)d_in[2];
    const int*   memb = prov + E_;
    const float* W1_m = (const float*)d_in[3];
    const float* a_src1_m = (const float*)d_in[4];
    const float* a_dst1_m = (const float*)d_in[5];
    const float* b1_m = (const float*)d_in[6];
    const float* W2_m = (const float*)d_in[7];
    const float* a_src2_m = (const float*)d_in[8];
    const float* a_dst2_m = (const float*)d_in[9];
    const float* b2_m = (const float*)d_in[10];
    const float* W1_p = (const float*)d_in[11];
    const float* a_src1_p = (const float*)d_in[12];
    const float* a_dst1_p = (const float*)d_in[13];
    const float* b1_p = (const float*)d_in[14];
    const float* W2_p = (const float*)d_in[15];
    const float* a_src2_p = (const float*)d_in[16];
    const float* a_dst2_p = (const float*)d_in[17];
    const float* b2_p = (const float*)d_in[18];
    const float* Wd_m = (const float*)d_in[19];
    const float* bd_m = (const float*)d_in[20];
    const float* Wd_p = (const float*)d_in[21];
    const float* bd_p = (const float*)d_in[22];

    // workspace layout (~80 MB)
    char* p = (char*)d_ws;
    auto alloc = [&](size_t bytes) { void* q = (void*)p; p += (bytes + 255) & ~(size_t)255; return q; };
    float* h1     = (float*)alloc((size_t)N_ * 128 * 4);
    float* xm     = (float*)alloc((size_t)N_ * 128 * 4);
    float* zm     = (float*)alloc((size_t)N_ * 64 * 4);
    float* zp     = (float*)alloc((size_t)N_ * 64 * 4);
    float* s1     = (float*)alloc((size_t)N_ * 4 * 4);
    float* d1     = (float*)alloc((size_t)N_ * 4 * 4);
    float* s2     = (float*)alloc((size_t)N_ * 4);
    float* d2     = (float*)alloc((size_t)N_ * 4);
    int*   cnt    = (int*)alloc((size_t)N_ * 4);
    int*   roff   = (int*)alloc((size_t)(N_ + 1) * 4);
    int*   cursor = (int*)alloc((size_t)N_ * 4);
    int*   colA   = (int*)alloc((size_t)E_ * 4);
    int*   bsum   = (int*)alloc(1024 * 4);
    int*   boffs  = (int*)alloc(1024 * 4);
    float* h2 = h1;   // overlay: h1 dead once layer-1 aggregation is done

    const int nb = (N_ + 1023) / 1024;

    for (int side = 0; side < 2; ++side) {
        const int* dstArr = (side == 0) ? memb : prov;
        const int* srcArr = (side == 0) ? prov : memb;
        const float* X   = (side == 0) ? x_member : x_provider;
        const float* W1  = (side == 0) ? W1_m : W1_p;
        const float* as1 = (side == 0) ? a_src1_m : a_src1_p;
        const float* ad1 = (side == 0) ? a_dst1_m : a_dst1_p;
        const float* b1  = (side == 0) ? b1_m : b1_p;
        const float* W2  = (side == 0) ? W2_m : W2_p;
        const float* as2 = (side == 0) ? a_src2_m : a_src2_p;
        const float* ad2 = (side == 0) ? a_dst2_m : a_dst2_p;
        const float* b2  = (side == 0) ? b2_m : b2_p;
        float* z = (side == 0) ? zm : zp;

        // CSR by destination
        hipMemsetAsync(cnt, 0, (size_t)N_ * 4, stream);
        hipMemsetAsync(cursor, 0, (size_t)N_ * 4, stream);
        count_kernel<<<(E_ + 255) / 256, 256, 0, stream>>>(dstArr, cnt, E_);
        chunk_sum_kernel<<<nb, 1024, 0, stream>>>(cnt, bsum, N_);
        scan_blocks_kernel<<<1, 1024, 0, stream>>>(bsum, boffs, roff, nb, N_);
        scan_chunk_kernel<<<nb, 1024, 0, stream>>>(cnt, boffs, roff, N_);
        scatter_kernel<<<(E_ + 255) / 256, 256, 0, stream>>>(srcArr, dstArr, roff, cursor, colA, E_);

        // layer 1: GEMM -> s/d -> softmax-aggregate (+bias, ELU)
        gemm_kernel<128, 128, false><<<(N_ + 63) / 64, 256, 0, stream>>>(X, W1, nullptr, h1, N_);
        sd_kernel<128, 4><<<(N_ * 4 + 255) / 256, 256, 0, stream>>>(h1, as1, ad1, s1, d1, N_);
        agg_kernel<128, 4, true><<<(N_ + 3) / 4, 256, 0, stream>>>(h1, s1, d1, roff, colA, b1, xm, N_);

        // layer 2
        gemm_kernel<128, 64, false><<<(N_ + 63) / 64, 256, 0, stream>>>(xm, W2, nullptr, h2, N_);
        sd_kernel<64, 1><<<(N_ + 255) / 256, 256, 0, stream>>>(h2, as2, ad2, s2, d2, N_);
        agg_kernel<64, 1, false><<<(N_ + 3) / 4, 256, 0, stream>>>(h2, s2, d2, roff, colA, b2, z, N_);
    }

    // decoders + edge logits
    float* out = (float*)d_out;
    gemm_kernel<64, 128, true><<<(N_ + 63) / 64, 256, 0, stream>>>(zm, Wd_m, bd_m, out, N_);
    gemm_kernel<64, 128, true><<<(N_ + 63) / 64, 256, 0, stream>>>(zp, Wd_p, bd_p, out + (size_t)N_ * 128, N_);
    logits_kernel<<<(E_ + 3) / 4, 256, 0, stream>>>(zp, zm, prov, memb, out + (size_t)N_ * 128 * 2, E_);
}

// Round 4
// 856.541 us; speedup vs baseline: 1.1104x; 1.1104x over previous
//
#include <hip/hip_runtime.h>
#include <hip/hip_bf16.h>
#include <stdint.h>

// ---------------- GEMM: out[n,COUT] = X[n,K] @ W[K,COUT] (+bias), fp32 ----------------
template<int K, int COUT, bool ADD_BIAS>
__global__ __launch_bounds__(256) void gemm_kernel(const float* __restrict__ X,
                                                   const float* __restrict__ W,
                                                   const float* __restrict__ bias,
                                                   float* __restrict__ out, int n)
{
    constexpr int KC   = 64;
    constexpr int CPT  = (COUT >= 128) ? 8 : 4;
    constexpr int TX   = COUT / CPT;              // 16
    constexpr int TY   = 256 / TX;                // 16
    constexpr int ROWS = TY * 4;                  // 64

    __shared__ float Wl[KC * COUT];               // <= 32 KB
    __shared__ float Xl[KC * ROWS];               // 16 KB, TRANSPOSED [k][row]

    const int tid  = threadIdx.x;
    const int row0 = blockIdx.x * ROWS;
    const int tx = tid % TX, ty = tid / TX;
    const int c0 = tx * CPT;

    float acc[4][CPT];
    #pragma unroll
    for (int i = 0; i < 4; ++i)
        #pragma unroll
        for (int j = 0; j < CPT; ++j) acc[i][j] = 0.f;

    for (int k0 = 0; k0 < K; k0 += KC) {
        for (int i = tid; i < KC * COUT / 4; i += 256) {
            int e0 = i * 4;
            int r = e0 / COUT, c = e0 - r * COUT;
            reinterpret_cast<float4*>(Wl)[i] =
                *reinterpret_cast<const float4*>(W + (size_t)(k0 + r) * COUT + c);
        }
        for (int i = tid; i < ROWS * KC / 4; i += 256) {
            int r = i / (KC / 4), c4 = i - r * (KC / 4);
            int gr = row0 + r;
            float4 v = make_float4(0.f, 0.f, 0.f, 0.f);
            if (gr < n) v = *reinterpret_cast<const float4*>(X + (size_t)gr * K + k0 + c4 * 4);
            int cb = c4 * 4;
            Xl[(cb + 0) * ROWS + r] = v.x;
            Xl[(cb + 1) * ROWS + r] = v.y;
            Xl[(cb + 2) * ROWS + r] = v.z;
            Xl[(cb + 3) * ROWS + r] = v.w;
        }
        __syncthreads();

        #pragma unroll 16
        for (int kk = 0; kk < KC; ++kk) {
            float b[CPT];
            #pragma unroll
            for (int j = 0; j < CPT; ++j) b[j] = Wl[kk * COUT + c0 + j];
            float4 a4 = *reinterpret_cast<const float4*>(Xl + kk * ROWS + ty * 4);
            float a[4] = {a4.x, a4.y, a4.z, a4.w};
            #pragma unroll
            for (int i = 0; i < 4; ++i)
                #pragma unroll
                for (int j = 0; j < CPT; ++j)
                    acc[i][j] = fmaf(a[i], b[j], acc[i][j]);
        }
        __syncthreads();
    }

    #pragma unroll
    for (int i = 0; i < 4; ++i) {
        int gr = row0 + ty * 4 + i;
        if (gr < n) {
            #pragma unroll
            for (int j = 0; j < CPT; ++j) {
                float v = acc[i][j];
                if constexpr (ADD_BIAS) v += bias[c0 + j];
                out[(size_t)gr * COUT + c0 + j] = v;
            }
        }
    }
}

// ---------------- attention scalars ----------------
template<int C, int H>
__global__ __launch_bounds__(256) void sd_kernel(const float* __restrict__ hfeat,
                                                 const float* __restrict__ asrc,
                                                 const float* __restrict__ adst,
                                                 float* __restrict__ s,
                                                 float* __restrict__ d, int n)
{
    constexpr int CH = C / H;
    int t = blockIdx.x * 256 + threadIdx.x;
    if (t >= n * H) return;
    int node = t / H, hh = t - (t / H) * H;
    const float* hp = hfeat + (size_t)node * C + hh * CH;
    float as = 0.f, ad = 0.f;
    #pragma unroll
    for (int c = 0; c < CH; ++c) {
        float hv = hp[c];
        as = fmaf(hv, asrc[hh * CH + c], as);
        ad = fmaf(hv, adst[hh * CH + c], ad);
    }
    s[t] = as; d[t] = ad;
}

// ---------------- CSR build (both sides fused) ----------------
__global__ __launch_bounds__(256) void count_both_kernel(const int* __restrict__ prov,
                                                         const int* __restrict__ memb,
                                                         int* __restrict__ cnt2, int e, int n)
{
    int t = blockIdx.x * 256 + threadIdx.x;
    if (t < e) {
        atomicAdd(&cnt2[memb[t]], 1);
        atomicAdd(&cnt2[n + prov[t]], 1);
    }
}

__global__ __launch_bounds__(1024) void chunk_sum_kernel(const int* __restrict__ cnt,
                                                         int* __restrict__ bsum, int n)
{
    __shared__ int red[1024];
    int i = blockIdx.x * 1024 + threadIdx.x;
    red[threadIdx.x] = (i < n) ? cnt[i] : 0;
    __syncthreads();
    for (int o = 512; o > 0; o >>= 1) {
        if (threadIdx.x < o) red[threadIdx.x] += red[threadIdx.x + o];
        __syncthreads();
    }
    if (threadIdx.x == 0) bsum[blockIdx.x] = red[0];
}

__global__ __launch_bounds__(1024) void scan_blocks_kernel(const int* __restrict__ bsum,
                                                           int* __restrict__ boffs,
                                                           int* __restrict__ roff,
                                                           int nb, int n)
{
    __shared__ int tmp[1024];
    int tid = threadIdx.x;
    int v = (tid < nb) ? bsum[tid] : 0;
    tmp[tid] = v; __syncthreads();
    for (int o = 1; o < 1024; o <<= 1) {
        int x = (tid >= o) ? tmp[tid - o] : 0;
        __syncthreads();
        tmp[tid] += x;
        __syncthreads();
    }
    boffs[tid] = tmp[tid] - v;
    if (tid == 0) roff[n] = tmp[1023];
}

__global__ __launch_bounds__(1024) void scan_chunk_kernel(const int* __restrict__ cnt,
                                                          const int* __restrict__ boffs,
                                                          int* __restrict__ roff, int n)
{
    __shared__ int tmp[1024];
    int tid = threadIdx.x;
    int i = blockIdx.x * 1024 + tid;
    int v = (i < n) ? cnt[i] : 0;
    tmp[tid] = v; __syncthreads();
    for (int o = 1; o < 1024; o <<= 1) {
        int x = (tid >= o) ? tmp[tid - o] : 0;
        __syncthreads();
        tmp[tid] += x;
        __syncthreads();
    }
    if (i < n) roff[i] = boffs[blockIdx.x] + tmp[tid] - v;
}

__global__ __launch_bounds__(256) void scatter_both_kernel(const int* __restrict__ prov,
                                                           const int* __restrict__ memb,
                                                           const int* __restrict__ roff2,
                                                           int* __restrict__ cursor2,
                                                           int* __restrict__ col, int e, int n)
{
    int t = blockIdx.x * 256 + threadIdx.x;
    if (t < e) {
        int p = prov[t], m = memb[t];
        int posM = roff2[m] + atomicAdd(&cursor2[m], 1);
        col[posM] = p;
        int posP = roff2[n + p] + atomicAdd(&cursor2[n + p], 1);
        col[posP] = m;
    }
}

// ---------------- GAT aggregation: one wave per destination node (3-pass, round-2) ----------------
template<int C, int H, bool ELU>
__global__ __launch_bounds__(256) void agg_kernel(const float* __restrict__ hfeat,
                                                  const float* __restrict__ sarr,
                                                  const float* __restrict__ darr,
                                                  const int* __restrict__ roff,
                                                  const int* __restrict__ col,
                                                  const float* __restrict__ bias,
                                                  float* __restrict__ out, int n)
{
    constexpr int CPL = C / 64;   // cols per lane (2 or 1)
    constexpr int CH  = C / H;
    const int wv   = (blockIdx.x * 256 + threadIdx.x) >> 6;
    const int lane = threadIdx.x & 63;
    if (wv >= n) return;
    const int i = wv;

    float dh[H], es[H], mh[H];
    #pragma unroll
    for (int hh = 0; hh < H; ++hh) dh[hh] = darr[(size_t)i * H + hh];
    #pragma unroll
    for (int hh = 0; hh < H; ++hh) {
        float e = sarr[(size_t)i * H + hh] + dh[hh];
        e = fmaxf(e, 0.2f * e);               // leaky_relu(0.2) -- self loop
        es[hh] = e; mh[hh] = e;
    }
    const int start = roff[i], end = roff[i + 1];

    // pass 1: segment max per head
    for (int base = start; base < end; base += 64) {
        int idx = base + lane;
        if (idx < end) {
            int src = col[idx];
            #pragma unroll
            for (int hh = 0; hh < H; ++hh) {
                float e = sarr[(size_t)src * H + hh] + dh[hh];
                e = fmaxf(e, 0.2f * e);
                mh[hh] = fmaxf(mh[hh], e);
            }
        }
    }
    #pragma unroll
    for (int hh = 0; hh < H; ++hh)
        for (int o = 32; o >= 1; o >>= 1)
            mh[hh] = fmaxf(mh[hh], __shfl_xor(mh[hh], o, 64));

    // pass 2: sum of exp
    float zh[H];
    #pragma unroll
    for (int hh = 0; hh < H; ++hh) zh[hh] = 0.f;
    for (int base = start; base < end; base += 64) {
        int idx = base + lane;
        if (idx < end) {
            int src = col[idx];
            #pragma unroll
            for (int hh = 0; hh < H; ++hh) {
                float e = sarr[(size_t)src * H + hh] + dh[hh];
                e = fmaxf(e, 0.2f * e);
                zh[hh] += __expf(e - mh[hh]);
            }
        }
    }
    #pragma unroll
    for (int hh = 0; hh < H; ++hh) {
        for (int o = 32; o >= 1; o >>= 1) zh[hh] += __shfl_xor(zh[hh], o, 64);
        zh[hh] += __expf(es[hh] - mh[hh]);    // self-loop term (uniform across lanes)
    }

    // lane-local head parameters
    const int c0 = lane * CPL;
    const int hd = c0 / CH;
    const float m_l  = mh[hd];
    const float invz = 1.f / (zh[hd] + 1e-16f);
    const float d_l  = dh[hd];

    float acc[CPL];
    {
        float aself = __expf(es[hd] - m_l) * invz;
        if constexpr (CPL == 2) {
            float2 hv = reinterpret_cast<const float2*>(hfeat + (size_t)i * C)[lane];
            acc[0] = aself * hv.x; acc[1] = aself * hv.y;
        } else {
            acc[0] = aself * hfeat[(size_t)i * C + lane];
        }
    }

    // pass 3: weighted accumulate, edge-serial within wave
    for (int base = start; base < end; base += 64) {
        int idx = base + lane;
        int srcL = (idx < end) ? col[idx] : 0;
        int cnt2 = min(64, end - base);
        for (int t = 0; t < cnt2; ++t) {
            int st = __shfl(srcL, t, 64);
            float e = sarr[(size_t)st * H + hd] + d_l;
            e = fmaxf(e, 0.2f * e);
            float a = __expf(e - m_l) * invz;
            if constexpr (CPL == 2) {
                float2 hv = reinterpret_cast<const float2*>(hfeat + (size_t)st * C)[lane];
                acc[0] = fmaf(a, hv.x, acc[0]);
                acc[1] = fmaf(a, hv.y, acc[1]);
            } else {
                acc[0] = fmaf(a, hfeat[(size_t)st * C + lane], acc[0]);
            }
        }
    }

    #pragma unroll
    for (int j = 0; j < CPL; ++j) {
        int c = c0 + j;
        float v = acc[j] + bias[c];
        if constexpr (ELU) v = (v > 0.f) ? v : (__expf(v) - 1.f);
        out[(size_t)i * C + c] = v;
    }
}

// ---------------- edge logits: 16 lanes/edge, grid-stride ----------------
__global__ __launch_bounds__(256) void logits_kernel(const float* __restrict__ zp,
                                                     const float* __restrict__ zm,
                                                     const int* __restrict__ prov,
                                                     const int* __restrict__ memb,
                                                     float* __restrict__ outv, int e)
{
    const int nw   = (gridDim.x * 256) >> 6;
    const int wv   = (blockIdx.x * 256 + threadIdx.x) >> 6;
    const int lane = threadIdx.x & 63;
    const int g = lane >> 4, q = lane & 15;
    for (int base = wv * 4; base < e; base += nw * 4) {
        int eidx = base + g;
        bool valid = eidx < e;
        int idx = valid ? eidx : (e - 1);
        int p = prov[idx], m = memb[idx];
        float4 a = *reinterpret_cast<const float4*>(zp + (size_t)p * 64 + q * 4);
        float4 b = *reinterpret_cast<const float4*>(zm + (size_t)m * 64 + q * 4);
        float v = a.x * b.x + a.y * b.y + a.z * b.z + a.w * b.w;
        #pragma unroll
        for (int o = 1; o < 16; o <<= 1) v += __shfl_xor(v, o, 64);
        if (q == 0 && valid) outv[eidx] = v;
    }
}

// ---------------- launch ----------------
extern "C" void kernel_launch(void* const* d_in, const int* in_sizes, int n_in,
                              void* d_out, int out_size, void* d_ws, size_t ws_size,
                              hipStream_t stream)
{
    const int N_ = in_sizes[0] / 128;
    const int E_ = in_sizes[2] / 2;

    const float* x_member   = (const float*)d_in[0];
    const float* x_provider = (const float*)d_in[1];
    const int*   prov = (const int*)d_in[2];
    const int*   memb = prov + E_;
    const float* W1_m = (const float*)d_in[3];
    const float* a_src1_m = (const float*)d_in[4];
    const float* a_dst1_m = (const float*)d_in[5];
    const float* b1_m = (const float*)d_in[6];
    const float* W2_m = (const float*)d_in[7];
    const float* a_src2_m = (const float*)d_in[8];
    const float* a_dst2_m = (const float*)d_in[9];
    const float* b2_m = (const float*)d_in[10];
    const float* W1_p = (const float*)d_in[11];
    const float* a_src1_p = (const float*)d_in[12];
    const float* a_dst1_p = (const float*)d_in[13];
    const float* b1_p = (const float*)d_in[14];
    const float* W2_p = (const float*)d_in[15];
    const float* a_src2_p = (const float*)d_in[16];
    const float* a_dst2_p = (const float*)d_in[17];
    const float* b2_p = (const float*)d_in[18];
    const float* Wd_m = (const float*)d_in[19];
    const float* bd_m = (const float*)d_in[20];
    const float* Wd_p = (const float*)d_in[21];
    const float* bd_p = (const float*)d_in[22];

    char* p = (char*)d_ws;
    auto alloc = [&](size_t bytes) { void* q = (void*)p; p += (bytes + 255) & ~(size_t)255; return q; };
    float* h1     = (float*)alloc((size_t)N_ * 128 * 4);
    float* xm     = (float*)alloc((size_t)N_ * 128 * 4);
    float* zm     = (float*)alloc((size_t)N_ * 64 * 4);
    float* zp     = (float*)alloc((size_t)N_ * 64 * 4);
    float* s1     = (float*)alloc((size_t)N_ * 4 * 4);
    float* d1     = (float*)alloc((size_t)N_ * 4 * 4);
    float* s2     = (float*)alloc((size_t)N_ * 4);
    float* d2     = (float*)alloc((size_t)N_ * 4);
    int*   cnt2   = (int*)alloc((size_t)2 * N_ * 4 * 2);   // cnt2[2N] + cursor2[2N]
    int*   cursor2 = cnt2 + 2 * N_;
    int*   roff2  = (int*)alloc((size_t)(2 * N_ + 1) * 4);
    int*   colA   = (int*)alloc((size_t)2 * E_ * 4);
    int*   bsum   = (int*)alloc(1024 * 4);
    int*   boffs  = (int*)alloc(1024 * 4);
    float* h2 = h1;

    const int n2 = 2 * N_;
    const int nb2 = (n2 + 1023) / 1024;

    // CSR for both sides, one pass
    hipMemsetAsync(cnt2, 0, (size_t)4 * N_ * 4, stream);
    count_both_kernel<<<(E_ + 255) / 256, 256, 0, stream>>>(prov, memb, cnt2, E_, N_);
    chunk_sum_kernel<<<nb2, 1024, 0, stream>>>(cnt2, bsum, n2);
    scan_blocks_kernel<<<1, 1024, 0, stream>>>(bsum, boffs, roff2, nb2, n2);
    scan_chunk_kernel<<<nb2, 1024, 0, stream>>>(cnt2, boffs, roff2, n2);
    scatter_both_kernel<<<(E_ + 255) / 256, 256, 0, stream>>>(prov, memb, roff2, cursor2, colA, E_, N_);

    for (int side = 0; side < 2; ++side) {
        const float* X   = (side == 0) ? x_member : x_provider;
        const float* W1  = (side == 0) ? W1_m : W1_p;
        const float* as1 = (side == 0) ? a_src1_m : a_src1_p;
        const float* ad1 = (side == 0) ? a_dst1_m : a_dst1_p;
        const float* b1  = (side == 0) ? b1_m : b1_p;
        const float* W2  = (side == 0) ? W2_m : W2_p;
        const float* as2 = (side == 0) ? a_src2_m : a_src2_p;
        const float* ad2 = (side == 0) ? a_dst2_m : a_dst2_p;
        const float* b2  = (side == 0) ? b2_m : b2_p;
        float* z = (side == 0) ? zm : zp;
        const int* roff = (side == 0) ? roff2 : (roff2 + N_);

        gemm_kernel<128, 128, false><<<(N_ + 63) / 64, 256, 0, stream>>>(X, W1, nullptr, h1, N_);
        sd_kernel<128, 4><<<(N_ * 4 + 255) / 256, 256, 0, stream>>>(h1, as1, ad1, s1, d1, N_);
        agg_kernel<128, 4, true><<<(N_ + 3) / 4, 256, 0, stream>>>(h1, s1, d1, roff, colA, b1, xm, N_);

        gemm_kernel<128, 64, false><<<(N_ + 63) / 64, 256, 0, stream>>>(xm, W2, nullptr, h2, N_);
        sd_kernel<64, 1><<<(N_ + 255) / 256, 256, 0, stream>>>(h2, as2, ad2, s2, d2, N_);
        agg_kernel<64, 1, false><<<(N_ + 3) / 4, 256, 0, stream>>>(h2, s2, d2, roff, colA, b2, z, N_);
    }

    float* out = (float*)d_out;
    gemm_kernel<64, 128, true><<<(N_ + 63) / 64, 256, 0, stream>>>(zm, Wd_m, bd_m, out, N_);
    gemm_kernel<64, 128, true><<<(N_ + 63) / 64, 256, 0, stream>>>(zp, Wd_p, bd_p, out + (size_t)N_ * 128, N_);
    logits_kernel<<<2048, 256, 0, stream>>>(zp, zm, prov, memb, out + (size_t)N_ * 128 * 2, E_);
}